// Round 11
// baseline (367.005 us; speedup 1.0000x reference)
//
#include <hip/hip_runtime.h>

// BitNetAttention on MI355X (gfx950).
// R1: XOR-swizzled LDS, fused QKV GEMM. R2/R3: S^T=K*Q^T in-lane softmax.
// R4: attn 512 threads, defer-max, exp2 softmax, setprio.
// R8: GEMMs on INT8 MFMA (mfma_i32_16x16x64_i8): -61us (BitNet integer-exact).
// R10: BK=128 + V^T fused into qkv + ropetab merged into wstats (364.7us).
// R11/R12: (regressed) attn two-state pipeline -> VGPR spill. Reverted R13.
// R14: (this) attn Ps-ELIMINATION via PV on v_mfma_f32_16x16x16_bf16:
//   S^T output layout (lane holds P[k2*16+quad*4+r][q=l15]) IS the K=16
//   B-fragment layout, so P feeds PV directly from registers -- no Ps LDS
//   (80->64KB), no ds_write/ds_read round-trip, no cross-lane exchange.
//   V^T read as ds_read_b64 (same 16B-chunk swizzle). MFMA16 via inline asm
//   (instruction per cdna4_isa §10); operand data-deps order it after the
//   compiler-tracked loads. Plus: wsign merged into rqnorm<3> (prep_kernel,
//   both depend only on wstats) -- 7 -> 6 dispatches.

#define DI __device__ __forceinline__

using bf16   = __bf16;
using bf16x4 = __attribute__((ext_vector_type(4))) __bf16;
using bf16x8 = __attribute__((ext_vector_type(8))) __bf16;
using f32x4  = __attribute__((ext_vector_type(4))) float;
using i32x4  = __attribute__((ext_vector_type(4))) int;

DI void gl_lds16(void* lds, const void* g) {
  __builtin_amdgcn_global_load_lds((const __attribute__((address_space(1))) void*)g,
                                   (__attribute__((address_space(3))) void*)lds, 16, 0, 0);
}
DI float clampf(float x, float lo, float hi) { return fminf(fmaxf(x, lo), hi); }

// K=16 bf16 MFMA (cdna4_isa §10: v_mfma_f32_16x16x16_bf16, A/B = 2 VGPRs).
// Pure-register op: operand deps order it after the V ds_read (normal C++
// load -> compiler inserts the lgkm wait on the %2 input).
DI void mfma16(f32x4& acc, bf16x4 a, bf16x4 b) {
  asm("v_mfma_f32_16x16x16_bf16 %0, %1, %2, %0"
      : "+v"(acc) : "v"(a), "v"(b));
}

template <int N> DI void wait_vm() {
  if constexpr (N == 8)      asm volatile("s_waitcnt vmcnt(8)" ::: "memory");
  else if constexpr (N == 6) asm volatile("s_waitcnt vmcnt(6)" ::: "memory");
  else if constexpr (N == 4) asm volatile("s_waitcnt vmcnt(4)" ::: "memory");
  else                       asm volatile("s_waitcnt vmcnt(0)" ::: "memory");
}

DI float block_sum(float v, float* red, int lane, int w) {
#pragma unroll
  for (int o = 32; o > 0; o >>= 1) v += __shfl_xor(v, o, 64);
  __syncthreads();
  if (lane == 0) red[w] = v;
  __syncthreads();
  return red[0] + red[1] + red[2] + red[3];
}

// ---------------- weight stats + RoPE tables (merged) ----------------
__global__ void wstats_kernel(const float* wq, const float* wk, const float* wv,
                              const float* wo, float* stats, float* ct, float* st) {
  int t = threadIdx.x;
  int m = blockIdx.y;
  if (m == 4) {                       // RoPE table branch (whole block uniform)
    int idx = blockIdx.x * 256 + t;
#pragma unroll
    for (int k = 0; k < 2; ++k) {
      int e = idx + k * 65536;        // 131072 entries total
      int s = e >> 6, j = e & 63;
      float invf = powf(10000.f, -(float)j * (1.f / 64.f));
      float a = (float)s * invf;
      ct[s * 64 + j] = cosf(a);
      st[s * 64 + j] = sinf(a);
    }
    return;
  }
  __shared__ float red[4], red2[4];
  int lane = t & 63, w = t >> 6;
  const float* src; int n4;
  if (m == 0)      { src = wq; n4 = 1048576; }
  else if (m == 1) { src = wk; n4 = 524288;  }
  else if (m == 2) { src = wv; n4 = 524288;  }
  else             { src = wo; n4 = 1048576; }
  float s = 0.f, sa = 0.f;
  for (int i = blockIdx.x * 256 + t; i < n4; i += 256 * 256) {
    float4 v = ((const float4*)src)[i];
    s  += v.x + v.y + v.z + v.w;
    sa += fabsf(v.x) + fabsf(v.y) + fabsf(v.z) + fabsf(v.w);
  }
#pragma unroll
  for (int o = 32; o > 0; o >>= 1) { s += __shfl_xor(s, o, 64); sa += __shfl_xor(sa, o, 64); }
  if (lane == 0) { red[w] = s; red2[w] = sa; }
  __syncthreads();
  if (t == 0) {
    atomicAdd(&stats[2 * m],     red[0] + red[1] + red[2] + red[3]);
    atomicAdd(&stats[2 * m + 1], red2[0] + red2[1] + red2[2] + red2[3]);
  }
}

// ---- merged prep: rqnorm<3> (blocks 0..4095) + wsign (blocks 4096..8191) --
// Both depend only on wstats; fusing saves a dispatch gap.
__launch_bounds__(256)
__global__ void prep_kernel(const float* __restrict__ x,
                            const float* __restrict__ w0, const float* __restrict__ w1,
                            const float* __restrict__ w2,
                            char* a0, char* a1, char* a2,
                            float* r0, float* r1, float* r2,
                            const float* wq, const float* wk, const float* wv,
                            const float* wo,
                            char* sq, char* sk, char* sv, char* so,
                            const float* __restrict__ stats) {
  int t = threadIdx.x;
  if (blockIdx.x >= 4096) {
    // ---- ternary sign quant -> int8 ----
    int bid = blockIdx.x - 4096;
    int m = bid >> 10;
    const float* src; char* dst; int n4; float cinv;
    if (m == 0)      { src = wq; dst = sq; n4 = 1048576; cinv = 1.f / 4194304.f; }
    else if (m == 1) { src = wk; dst = sk; n4 = 524288;  cinv = 1.f / 2097152.f; }
    else if (m == 2) { src = wv; dst = sv; n4 = 524288;  cinv = 1.f / 2097152.f; }
    else             { src = wo; dst = so; n4 = 1048576; cinv = 1.f / 4194304.f; }
    float e = stats[2 * m] * cinv;
    for (int i = (bid & 1023) * 256 + t; i < n4; i += 1024 * 256) {
      float4 v = ((const float4*)src)[i];
      char4 o;
      o.x = v.x > e ? 1 : (v.x < e ? -1 : 0);
      o.y = v.y > e ? 1 : (v.y < e ? -1 : 0);
      o.z = v.z > e ? 1 : (v.z < e ? -1 : 0);
      o.w = v.w > e ? 1 : (v.w < e ? -1 : 0);
      ((char4*)dst)[i] = o;
    }
    return;
  }
  // ---- fused RMSNorm + 3-way activation quant -> int8 ----
  __shared__ float red[4];
  __shared__ float redm[4][3];
  int lane = t & 63, w = t >> 6;
  int row = blockIdx.x;
  const float* xr = x + (size_t)row * 2048;
  float4 u0 = ((const float4*)xr)[t * 2], u1 = ((const float4*)xr)[t * 2 + 1];
  float xs[8] = {u0.x, u0.y, u0.z, u0.w, u1.x, u1.y, u1.z, u1.w};
  float ss = 0.f;
#pragma unroll
  for (int e = 0; e < 8; ++e) { xs[e] = clampf(xs[e], -100.f, 100.f); ss += xs[e] * xs[e]; }
  float tot = block_sum(ss, red, lane, w);
  float var = fmaxf(tot * (1.f / 2048.f), 1e-5f);
  float inv = 1.f / sqrtf(var + 1e-5f);
#pragma unroll
  for (int e = 0; e < 8; ++e) xs[e] = clampf(xs[e] * inv, -10.f, 10.f);

  float y[3][8], am[3];
#pragma unroll
  for (int m = 0; m < 3; ++m) {
    const float* wt = (m == 0) ? w0 : (m == 1) ? w1 : w2;
    float4 b0 = ((const float4*)wt)[t * 2], b1 = ((const float4*)wt)[t * 2 + 1];
    float wv8[8] = {b0.x, b0.y, b0.z, b0.w, b1.x, b1.y, b1.z, b1.w};
    am[m] = 0.f;
#pragma unroll
    for (int e = 0; e < 8; ++e) {
      y[m][e] = clampf(wv8[e] * xs[e], -50.f, 50.f);
      am[m] = fmaxf(am[m], fabsf(y[m][e]));
    }
  }
#pragma unroll
  for (int o = 32; o > 0; o >>= 1)
#pragma unroll
    for (int m = 0; m < 3; ++m) am[m] = fmaxf(am[m], __shfl_xor(am[m], o, 64));
  if (lane == 0)
#pragma unroll
    for (int m = 0; m < 3; ++m) redm[w][m] = am[m];
  __syncthreads();
#pragma unroll
  for (int m = 0; m < 3; ++m) {
    char* a = (m == 0) ? a0 : (m == 1) ? a1 : a2;
    float* r = (m == 0) ? r0 : (m == 1) ? r1 : r2;
    float mx = fmaxf(fmaxf(redm[0][m], redm[1][m]), fmaxf(redm[2][m], redm[3][m]));
    float maxval = fmaxf(mx, 1e-4f);
    float sc = 127.f / maxval;
    union { char c[8]; int2 v; } pk;
#pragma unroll
    for (int e = 0; e < 8; ++e)
      pk.c[e] = (char)clampf(rintf(y[m][e] * sc), -128.f, 127.f);
    *(int2*)(a + (size_t)row * 2048 + t * 8) = pk.v;
    if (t == 0) r[row] = maxval * (1.f / 127.f);
  }
}

// ---------------- fused RMSNorm + activation quant -> int8 (1-way) ---------
template <int NW>
__launch_bounds__(256)
__global__ void rqnorm_kernel(const float* __restrict__ x,
                              const float* __restrict__ w0, const float* __restrict__ w1,
                              const float* __restrict__ w2,
                              char* a0, char* a1, char* a2,
                              float* r0, float* r1, float* r2) {
  __shared__ float red[4];
  __shared__ float redm[4][NW];
  int t = threadIdx.x, lane = t & 63, w = t >> 6;
  int row = blockIdx.x;
  const float* xr = x + (size_t)row * 2048;
  float4 u0 = ((const float4*)xr)[t * 2], u1 = ((const float4*)xr)[t * 2 + 1];
  float xs[8] = {u0.x, u0.y, u0.z, u0.w, u1.x, u1.y, u1.z, u1.w};
  float ss = 0.f;
#pragma unroll
  for (int e = 0; e < 8; ++e) { xs[e] = clampf(xs[e], -100.f, 100.f); ss += xs[e] * xs[e]; }
  float tot = block_sum(ss, red, lane, w);
  float var = fmaxf(tot * (1.f / 2048.f), 1e-5f);
  float inv = 1.f / sqrtf(var + 1e-5f);
#pragma unroll
  for (int e = 0; e < 8; ++e) xs[e] = clampf(xs[e] * inv, -10.f, 10.f);

  float y[NW][8], am[NW];
#pragma unroll
  for (int m = 0; m < NW; ++m) {
    const float* wt = (m == 0) ? w0 : (m == 1) ? w1 : w2;
    float4 b0 = ((const float4*)wt)[t * 2], b1 = ((const float4*)wt)[t * 2 + 1];
    float wv8[8] = {b0.x, b0.y, b0.z, b0.w, b1.x, b1.y, b1.z, b1.w};
    am[m] = 0.f;
#pragma unroll
    for (int e = 0; e < 8; ++e) {
      y[m][e] = clampf(wv8[e] * xs[e], -50.f, 50.f);
      am[m] = fmaxf(am[m], fabsf(y[m][e]));
    }
  }
#pragma unroll
  for (int o = 32; o > 0; o >>= 1)
#pragma unroll
    for (int m = 0; m < NW; ++m) am[m] = fmaxf(am[m], __shfl_xor(am[m], o, 64));
  if (lane == 0)
#pragma unroll
    for (int m = 0; m < NW; ++m) redm[w][m] = am[m];
  __syncthreads();
#pragma unroll
  for (int m = 0; m < NW; ++m) {
    char* a = (m == 0) ? a0 : (m == 1) ? a1 : a2;
    float* r = (m == 0) ? r0 : (m == 1) ? r1 : r2;
    float mx = fmaxf(fmaxf(redm[0][m], redm[1][m]), fmaxf(redm[2][m], redm[3][m]));
    float maxval = fmaxf(mx, 1e-4f);
    float sc = 127.f / maxval;
    union { char c[8]; int2 v; } pk;
#pragma unroll
    for (int e = 0; e < 8; ++e)
      pk.c[e] = (char)clampf(rintf(y[m][e] * sc), -128.f, 127.f);
    *(int2*)(a + (size_t)row * 2048 + t * 8) = pk.v;
    if (t == 0) r[row] = maxval * (1.f / 127.f);
  }
}

// ---------------- INT8 GEMM pipeline core, BK=128 (frozen) -----------------
template <int BM, int BN>
DI void mm_pipe(const char* __restrict__ Ag0, const char* __restrict__ Bg0,
                char* As, char* Bs, int t, i32x4 (&acc)[BM / 64][BN / 32]) {
  constexpr int MR = BM / 64, NR = BN / 32;
  constexpr int AL = BM / 64, BL = BN / 64;    // 16B chunks/thread/tile
  constexpr int NT = 16;                       // K = 2048 / 128
  int lane = t & 63, l15 = lane & 15, quad = lane >> 4;
  int wv = t >> 6, wm = wv >> 1, wn = wv & 1;
  const char* agp[AL]; const char* bgp[BL];
#pragma unroll
  for (int i = 0; i < AL; ++i) {
    int c = t + i * 512, row = c >> 3, cr = c & 7;
    agp[i] = Ag0 + (size_t)row * 2048 + (cr ^ (row & 7)) * 16;
  }
#pragma unroll
  for (int i = 0; i < BL; ++i) {
    int c = t + i * 512, row = c >> 3, cr = c & 7;
    bgp[i] = Bg0 + (size_t)row * 2048 + (cr ^ (row & 7)) * 16;
  }
  auto stage = [&](int buf, int kt) {
    int kb = kt * 128;
#pragma unroll
    for (int i = 0; i < AL; ++i)
      gl_lds16(As + buf * (BM * 128) + (t + i * 512) * 16, agp[i] + kb);
#pragma unroll
    for (int i = 0; i < BL; ++i)
      gl_lds16(Bs + buf * (BN * 128) + (t + i * 512) * 16, bgp[i] + kb);
  };
  stage(0, 0);
  stage(1, 1);
  int arow = wm * (BM / 4) + l15;
  int brow = wn * (BN / 2) + l15;
  int sa = arow & 7, sb = brow & 7;
  for (int kt = 0; kt < NT; ++kt) {
    int cur = kt & 1;
    if (kt == NT - 1) wait_vm<0>(); else wait_vm<AL + BL>();
    __builtin_amdgcn_sched_barrier(0);
    __builtin_amdgcn_s_barrier();
    __builtin_amdgcn_sched_barrier(0);
    const char* Ac = As + cur * (BM * 128);
    const char* Bc = Bs + cur * (BN * 128);
    __builtin_amdgcn_s_setprio(1);
#pragma unroll
    for (int ks = 0; ks < 2; ++ks) {
      int aco = ((ks * 4 + quad) ^ sa) * 16;
      int bco = ((ks * 4 + quad) ^ sb) * 16;
      i32x4 af[MR], bfr[NR];
#pragma unroll
      for (int m = 0; m < MR; ++m)
        af[m] = *(const i32x4*)(Ac + (arow + m * 16) * 128 + aco);
#pragma unroll
      for (int n = 0; n < NR; ++n)
        bfr[n] = *(const i32x4*)(Bc + (brow + n * 16) * 128 + bco);
#pragma unroll
      for (int m = 0; m < MR; ++m)
#pragma unroll
        for (int n = 0; n < NR; ++n)
          acc[m][n] = __builtin_amdgcn_mfma_i32_16x16x64_i8(af[m], bfr[n], acc[m][n], 0, 0, 0);
    }
    __builtin_amdgcn_s_setprio(0);
    __builtin_amdgcn_sched_barrier(0);
    __builtin_amdgcn_s_barrier();
    __builtin_amdgcn_sched_barrier(0);
    if (kt + 2 < NT) stage(cur, kt + 2);
  }
}

// ---------------- fused QKV projection GEMM (256x256 tiles, i8, BK=128) ----
__launch_bounds__(512, 2)
__global__ void qkv_gemm(const char* __restrict__ Aq, const char* __restrict__ Ak,
                         const char* __restrict__ Av, const char* __restrict__ Ball,
                         const float* __restrict__ rq, const float* __restrict__ rk,
                         const float* __restrict__ rv, const float* __restrict__ stats,
                         bf16* __restrict__ qr, bf16* __restrict__ kr,
                         bf16* __restrict__ vt,
                         const float* __restrict__ ct, const float* __restrict__ st) {
  __shared__ char As[2 * 256 * 128];  // 64 KB
  __shared__ char Bs[2 * 256 * 128];  // 64 KB  (128 KB total, 1 block/CU)
  int t = threadIdx.x;
  int bid = blockIdx.x;               // 256 blocks
  int swz = (bid & 7) * 32 + (bid >> 3);   // XCD-contiguous chunks (256%8==0)
  int x = swz >> 4, mt = swz & 15;
  int m0 = mt * 256;
  const char* A; const float* rs; float sw;
  if (x < 8)       { A = Aq; rs = rq; sw = stats[1] * (1.f / 4194304.f); }
  else if (x < 12) { A = Ak; rs = rk; sw = stats[3] * (1.f / 2097152.f); }
  else             { A = Av; rs = rv; sw = stats[5] * (1.f / 2097152.f); }
  sw = fmaxf(sw, 1e-8f);
  i32x4 acc[4][8] = {};
  mm_pipe<256, 256>(A + (size_t)m0 * 2048, Ball + (size_t)(x * 256) * 2048, As, Bs, t, acc);

  int lane = t & 63, l15 = lane & 15, quad = lane >> 4;
  int wv = t >> 6, wm = wv >> 1, wn = wv & 1;   // wave cols = wn*128 (one head)
  if (x < 12) {
    // Q pre-scaled by (1/sqrt(128))*log2(e): attn softmax runs in exp2 domain.
    constexpr float QROPE = 0.08838834764831845f * 1.4426950408889634f;
    float qmul = (x < 8) ? QROPE : 1.f;
    bf16* outb = (x < 8) ? qr : kr;
    int h = (x < 8) ? (x * 2 + wn) : ((x - 8) * 2 + wn);
    int nh = (x < 8) ? 16 : 8;
#pragma unroll
    for (int m = 0; m < 4; ++m)
#pragma unroll
      for (int r = 0; r < 4; ++r) {
        int row = m0 + wm * 64 + m * 16 + quad * 4 + r;
        float rsc = rs[row] * sw * qmul;
        int s = row & 2047, b = row >> 11;
        size_t base = ((size_t)(b * nh + h) * 2048 + s) * 128;
#pragma unroll
        for (int n = 0; n < 4; ++n) {
          int d = n * 16 + l15;
          float x1 = (float)acc[m][n][r] * rsc;
          float x2 = (float)acc[m][n + 4][r] * rsc;
          float c = ct[s * 64 + d], sn = st[s * 64 + d];
          outb[base + d]      = (bf16)(x1 * c - x2 * sn);
          outb[base + d + 64] = (bf16)(x2 * c + x1 * sn);
        }
      }
  } else {
    // V^T epilogue: wave's 128 cols = one kv-head; 4 consecutive tokens per
    // lane (r) -> bf16x4 store at V^T[(b*8+kvh)*128 + d][s0..s0+3].
    int n0g = (x - 12) * 256 + wn * 128;
    int kvh = n0g >> 7;
    int btok = m0 >> 11;
    int s0 = (m0 & 2047) + wm * 64 + quad * 4;
#pragma unroll
    for (int m = 0; m < 4; ++m)
#pragma unroll
      for (int n = 0; n < 8; ++n) {
        int d = n * 16 + l15;
        bf16x4 pk;
#pragma unroll
        for (int r = 0; r < 4; ++r) {
          int row = m0 + wm * 64 + m * 16 + quad * 4 + r;
          pk[r] = (bf16)((float)acc[m][n][r] * (rs[row] * sw));
        }
        *(bf16x4*)(vt + ((size_t)(btok * 8 + kvh) * 128 + d) * 2048 + s0 + m * 16) = pk;
      }
  }
}

// ---------------- O projection GEMM (128x256 tiles, i8, BK=128) ------------
__launch_bounds__(512, 2)
__global__ void gemm_o(const char* __restrict__ A, const char* __restrict__ Bw,
                       const float* __restrict__ rs, const float* __restrict__ stats,
                       float* __restrict__ out) {
  __shared__ char As[2 * 128 * 128];  // 32 KB
  __shared__ char Bs[2 * 256 * 128];  // 64 KB  (96 KB total)
  int t = threadIdx.x;
  int bid = blockIdx.x;               // 256 blocks
  int swz = (bid & 7) * 32 + (bid >> 3);
  int x = swz & 7, mt = swz >> 3;     // n-tile 0..7, m-tile 0..31
  int m0 = mt * 128, n0 = x * 256;
  i32x4 acc[2][8] = {};
  mm_pipe<128, 256>(A + (size_t)m0 * 2048, Bw + (size_t)n0 * 2048, As, Bs, t, acc);
  float sw = fmaxf(stats[7] * (1.f / 4194304.f), 1e-8f);
  int lane = t & 63, l15 = lane & 15, quad = lane >> 4;
  int wv = t >> 6, wm = wv >> 1, wn = wv & 1;
#pragma unroll
  for (int m = 0; m < 2; ++m)
#pragma unroll
    for (int r = 0; r < 4; ++r) {
      int row = m0 + wm * 32 + m * 16 + quad * 4 + r;
      float rsc = rs[row] * sw;
#pragma unroll
      for (int n = 0; n < 8; ++n)
        out[(size_t)row * 2048 + n0 + wn * 128 + n * 16 + l15] = (float)acc[m][n][r] * rsc;
    }
}

// ---------------- flash attention, S^T formulation, Ps-free PV -------------
// Softmax leaves lane with P[k2*16+quad*4+r][q=l15] as bf16x4 pkv[k2] --
// exactly the B-fragment of mfma_f32_16x16x16_bf16 (n=l15, k=quad*4+j).
// PV: per (k2,dt): vf = V^T[d=dt*16+l15][k2*16+quad*4 ..+3] (ds_read_b64,
// swizzled 16B chunk (k2*2+(quad>>1))^(row&7), half-chunk (quad&1)*8B);
// Oa[dt] = mfma16(vf, pkv[k2], Oa[dt]). No Ps buffer (LDS 80->64KB), no
// write->read chain. C/D layout is shape-determined -> epilogue unchanged.
__launch_bounds__(512, 4)
__global__ void attn_kernel(const bf16* __restrict__ Q, const bf16* __restrict__ Kc,
                            const bf16* __restrict__ Vt, const float* __restrict__ mask,
                            float* __restrict__ Oout) {
  constexpr float L2E  = 1.4426950408889634f;
  constexpr float DTHR = 8.f * L2E;
  __shared__ bf16 Ks[2][64 * 128];
  __shared__ bf16 Vs[2][128 * 64];
  int t = threadIdx.x, w = t >> 6, lane = t & 63;
  int l15 = lane & 15, quad = lane >> 4;
  int bh = blockIdx.y, b = bh >> 4, h = bh & 15, kvh = h >> 1;
  int q0 = blockIdx.x * 128;
  const bf16* Qb = Q + (size_t)(b * 16 + h) * 2048 * 128;
  const bf16* Kb = Kc + (size_t)(b * 8 + kvh) * 2048 * 128;
  const bf16* Vb = Vt + (size_t)(b * 8 + kvh) * 128 * 2048;

  int qloc = w * 16 + l15;
  int qg = q0 + qloc;

  bf16x8 qf[4];
#pragma unroll
  for (int kc = 0; kc < 4; ++kc)
    qf[kc] = *(const bf16x8*)(Qb + (size_t)qg * 128 + kc * 32 + quad * 8);

  f32x4 Oa[8] = {};
  float mrow = -1e30f, lrow = 0.f;

  auto stage = [&](int buf, int kt) {
    int kk0 = kt * 64;
#pragma unroll
    for (int i = 0; i < 2; ++i) {
      int c = t + i * 512;
      int kr = c >> 4, c16 = c & 15;
      gl_lds16(&Ks[buf][c * 8],
               Kb + (size_t)(kk0 + kr) * 128 + ((c16 ^ (kr & 15)) * 8));
    }
#pragma unroll
    for (int i = 0; i < 2; ++i) {
      int c = t + i * 512;
      int vr = c >> 3, c8 = c & 7;
      gl_lds16(&Vs[buf][c * 8],
               Vb + (size_t)vr * 2048 + kk0 + ((c8 ^ (vr & 7)) * 8));
    }
  };

  stage(0, 0);

  f32x4 mv[4];
#pragma unroll
  for (int k2 = 0; k2 < 4; ++k2)
    mv[k2] = *(const f32x4*)(mask + (size_t)qg * 2048 + k2 * 16 + quad * 4);

  for (int kt = 0; kt < 32; ++kt) {
    int cur = kt & 1;
    __syncthreads();
    if (kt < 31) stage(cur ^ 1, kt + 1);

    f32x4 Sacc[4] = {};
    __builtin_amdgcn_s_setprio(1);
#pragma unroll
    for (int kc = 0; kc < 4; ++kc) {
      bf16x8 kf[4];
#pragma unroll
      for (int k2 = 0; k2 < 4; ++k2)
        kf[k2] = *(const bf16x8*)(&Ks[cur][(k2 * 16 + l15) * 128 + (((kc * 4 + quad) ^ l15) * 8)]);
#pragma unroll
      for (int k2 = 0; k2 < 4; ++k2)
        Sacc[k2] = __builtin_amdgcn_mfma_f32_16x16x32_bf16(kf[k2], qf[kc], Sacc[k2], 0, 0, 0);
    }
    __builtin_amdgcn_s_setprio(0);

#pragma unroll
    for (int k2 = 0; k2 < 4; ++k2)
#pragma unroll
      for (int r = 0; r < 4; ++r)
        Sacc[k2][r] = fmaf(mv[k2][r], L2E, Sacc[k2][r]);
    f32x4 vm;
#pragma unroll
    for (int r = 0; r < 4; ++r)
      vm[r] = fmaxf(fmaxf(Sacc[0][r], Sacc[1][r]), fmaxf(Sacc[2][r], Sacc[3][r]));
    float mx = fmaxf(fmaxf(vm[0], vm[1]), fmaxf(vm[2], vm[3]));
    mx = fmaxf(mx, __shfl_xor(mx, 16, 64));
    mx = fmaxf(mx, __shfl_xor(mx, 32, 64));
    if (!__all(mx <= mrow + DTHR)) {
      float mnew = fmaxf(mrow, mx);
      float alpha = exp2f(mrow - mnew);
      mrow = mnew;
      lrow *= alpha;
#pragma unroll
      for (int dt = 0; dt < 8; ++dt) Oa[dt] *= alpha;
    }
    bf16x4 pkv[4];
    f32x4 vs = {0.f, 0.f, 0.f, 0.f};
#pragma unroll
    for (int k2 = 0; k2 < 4; ++k2) {
#pragma unroll
      for (int r = 0; r < 4; ++r) {
        float p = exp2f(Sacc[k2][r] - mrow);
        vs[r] += p;
        pkv[k2][r] = (bf16)p;
      }
    }
    float rsum = (vs[0] + vs[1]) + (vs[2] + vs[3]);
    rsum += __shfl_xor(rsum, 16, 64);
    rsum += __shfl_xor(rsum, 32, 64);
    lrow += rsum;

    if (kt < 31) {
      int kk1 = (kt + 1) * 64;
#pragma unroll
      for (int k2 = 0; k2 < 4; ++k2)
        mv[k2] = *(const f32x4*)(mask + (size_t)qg * 2048 + kk1 + k2 * 16 + quad * 4);
    }

    // ---- PV, register-P: O^T += V^T(k2-slice) x P(k2-slice) ----
    __builtin_amdgcn_s_setprio(1);
#pragma unroll
    for (int k2 = 0; k2 < 4; ++k2) {
      int chnk_base = k2 * 2 + (quad >> 1);
      int hoff = (quad & 1) * 4;
#pragma unroll
      for (int dt = 0; dt < 8; ++dt) {
        int row = dt * 16 + l15;
        bf16x4 vf = *(const bf16x4*)(&Vs[cur][row * 64 + ((chnk_base ^ (row & 7)) * 8) + hoff]);
        mfma16(Oa[dt], vf, pkv[k2]);
      }
    }
    __builtin_amdgcn_s_setprio(0);
  }

  float inv = 1.f / lrow;
  int token = b * 2048 + qg;
#pragma unroll
  for (int dt = 0; dt < 8; ++dt) {
    f32x4 o = Oa[dt] * inv;
    *(f32x4*)(Oout + (size_t)token * 2048 + h * 128 + dt * 16 + quad * 4) = o;
  }
}

// ---------------- launch ----------------
extern "C" void kernel_launch(void* const* d_in, const int* in_sizes, int n_in,
                              void* d_out, int out_size, void* d_ws, size_t ws_size,
                              hipStream_t stream) {
  const float* hidden = (const float*)d_in[0];
  const float* mask   = (const float*)d_in[1];
  const float* wq = (const float*)d_in[2];
  const float* wk = (const float*)d_in[3];
  const float* wv = (const float*)d_in[4];
  const float* wo = (const float*)d_in[5];
  const float* nq = (const float*)d_in[6];
  const float* nk = (const float*)d_in[7];
  const float* nv = (const float*)d_in[8];
  const float* no = (const float*)d_in[9];
  float* out = (float*)d_out;
  char* ws = (char*)d_ws;

  // i8 weights: SQ|SK|SV|SO contiguous (Ball = SQ base).
  constexpr size_t O_STATS = 0;
  constexpr size_t O_CT    = 256;
  constexpr size_t O_ST    = O_CT  + 524288;
  constexpr size_t O_SQ    = O_ST  + 524288;
  constexpr size_t O_SK    = O_SQ  + 4194304;
  constexpr size_t O_SV    = O_SK  + 2097152;
  constexpr size_t O_SO    = O_SV  + 2097152;
  constexpr size_t O_RSQ   = O_SO  + 4194304;
  constexpr size_t O_RSK   = O_RSQ + 16384;
  constexpr size_t O_RSV   = O_RSK + 16384;
  constexpr size_t O_RSO   = O_RSV + 16384;
  constexpr size_t O_AQQ   = O_RSO + 16384;     // i8 [4096][2048]
  constexpr size_t O_AQK   = O_AQQ + 8388608;
  constexpr size_t O_AQV   = O_AQK + 8388608;
  constexpr size_t O_QR    = O_AQV + 8388608;   // bf16 [2,16,2048,128]
  constexpr size_t O_KR    = O_QR  + 16777216;  // bf16 [2,8,2048,128]
  constexpr size_t O_VT    = O_KR  + 8388608;   // bf16 [2,8,128,2048]
  constexpr size_t O_ATTN  = O_VT  + 8388608;   // fp32 [4096,2048]
  constexpr size_t O_AQO   = O_AQQ;             // alias: i8, AQQ dead post-qkv

  float* stats = (float*)(ws + O_STATS);
  float* ct = (float*)(ws + O_CT);
  float* st = (float*)(ws + O_ST);

  (void)hipMemsetAsync(ws + O_STATS, 0, 256, stream);

  wstats_kernel<<<dim3(256, 5), 256, 0, stream>>>(wq, wk, wv, wo, stats, ct, st);

  prep_kernel<<<dim3(8192), 256, 0, stream>>>(hidden, nq, nk, nv,
      ws + O_AQQ, ws + O_AQK, ws + O_AQV,
      (float*)(ws + O_RSQ), (float*)(ws + O_RSK), (float*)(ws + O_RSV),
      wq, wk, wv, wo,
      ws + O_SQ, ws + O_SK, ws + O_SV, ws + O_SO, stats);

  qkv_gemm<<<dim3(256), 512, 0, stream>>>(
      ws + O_AQQ, ws + O_AQK, ws + O_AQV, ws + O_SQ,
      (const float*)(ws + O_RSQ), (const float*)(ws + O_RSK), (const float*)(ws + O_RSV),
      stats, (bf16*)(ws + O_QR), (bf16*)(ws + O_KR), (bf16*)(ws + O_VT), ct, st);

  attn_kernel<<<dim3(16, 32), 512, 0, stream>>>(
      (const bf16*)(ws + O_QR), (const bf16*)(ws + O_KR), (const bf16*)(ws + O_VT),
      mask, (float*)(ws + O_ATTN));

  rqnorm_kernel<1><<<dim3(4096), 256, 0, stream>>>((const float*)(ws + O_ATTN), no, no, no,
      ws + O_AQO, ws + O_AQO, ws + O_AQO,
      (float*)(ws + O_RSO), (float*)(ws + O_RSO), (float*)(ws + O_RSO));

  gemm_o<<<dim3(256), 512, 0, stream>>>(
      ws + O_AQO, ws + O_SO, (float*)(ws + O_RSO), stats, out);

  (void)in_sizes; (void)n_in; (void)out_size; (void)ws_size;
}

// Round 12
// 359.510 us; speedup vs baseline: 1.0208x; 1.0208x over previous
//
#include <hip/hip_runtime.h>

// BitNetAttention on MI355X (gfx950).
// R1: XOR-swizzled LDS, fused QKV GEMM. R2/R3: S^T=K*Q^T in-lane softmax.
// R4: attn 512 threads, defer-max, exp2 softmax, setprio.
// R8: GEMMs on INT8 MFMA (mfma_i32_16x16x64_i8): -61us (BitNet integer-exact).
// R10: BK=128 + V^T fused into qkv + ropetab merged into wstats (364.7us).
// R11/R12: (regressed) attn two-state pipeline -> VGPR spill. Reverted.
// R14: attn Ps-free PV via mfma16 regressed (+4.8us attn): ds_read_b64 has a
//      structural 4-way bank conflict (conflicts 2.1M->16.8M) and MFMA16 runs
//      at MFMA32 cycles (2x instrs). prep merge (rqnorm<3>+wsign) was -2.5us.
// R15: compose best-of: R13 attn (LDS-Ps PV, b128, MFMA32; proven 125.4us)
//      + R14 prep merge. Everything else frozen.

#define DI __device__ __forceinline__

using bf16   = __bf16;
using bf16x4 = __attribute__((ext_vector_type(4))) __bf16;
using bf16x8 = __attribute__((ext_vector_type(8))) __bf16;
using f32x4  = __attribute__((ext_vector_type(4))) float;
using i32x4  = __attribute__((ext_vector_type(4))) int;

DI void gl_lds16(void* lds, const void* g) {
  __builtin_amdgcn_global_load_lds((const __attribute__((address_space(1))) void*)g,
                                   (__attribute__((address_space(3))) void*)lds, 16, 0, 0);
}
DI float clampf(float x, float lo, float hi) { return fminf(fmaxf(x, lo), hi); }

template <int N> DI void wait_vm() {
  if constexpr (N == 8)      asm volatile("s_waitcnt vmcnt(8)" ::: "memory");
  else if constexpr (N == 6) asm volatile("s_waitcnt vmcnt(6)" ::: "memory");
  else if constexpr (N == 4) asm volatile("s_waitcnt vmcnt(4)" ::: "memory");
  else                       asm volatile("s_waitcnt vmcnt(0)" ::: "memory");
}

DI float block_sum(float v, float* red, int lane, int w) {
#pragma unroll
  for (int o = 32; o > 0; o >>= 1) v += __shfl_xor(v, o, 64);
  __syncthreads();
  if (lane == 0) red[w] = v;
  __syncthreads();
  return red[0] + red[1] + red[2] + red[3];
}

// ---------------- weight stats + RoPE tables (merged) ----------------
__global__ void wstats_kernel(const float* wq, const float* wk, const float* wv,
                              const float* wo, float* stats, float* ct, float* st) {
  int t = threadIdx.x;
  int m = blockIdx.y;
  if (m == 4) {                       // RoPE table branch (whole block uniform)
    int idx = blockIdx.x * 256 + t;
#pragma unroll
    for (int k = 0; k < 2; ++k) {
      int e = idx + k * 65536;        // 131072 entries total
      int s = e >> 6, j = e & 63;
      float invf = powf(10000.f, -(float)j * (1.f / 64.f));
      float a = (float)s * invf;
      ct[s * 64 + j] = cosf(a);
      st[s * 64 + j] = sinf(a);
    }
    return;
  }
  __shared__ float red[4], red2[4];
  int lane = t & 63, w = t >> 6;
  const float* src; int n4;
  if (m == 0)      { src = wq; n4 = 1048576; }
  else if (m == 1) { src = wk; n4 = 524288;  }
  else if (m == 2) { src = wv; n4 = 524288;  }
  else             { src = wo; n4 = 1048576; }
  float s = 0.f, sa = 0.f;
  for (int i = blockIdx.x * 256 + t; i < n4; i += 256 * 256) {
    float4 v = ((const float4*)src)[i];
    s  += v.x + v.y + v.z + v.w;
    sa += fabsf(v.x) + fabsf(v.y) + fabsf(v.z) + fabsf(v.w);
  }
#pragma unroll
  for (int o = 32; o > 0; o >>= 1) { s += __shfl_xor(s, o, 64); sa += __shfl_xor(sa, o, 64); }
  if (lane == 0) { red[w] = s; red2[w] = sa; }
  __syncthreads();
  if (t == 0) {
    atomicAdd(&stats[2 * m],     red[0] + red[1] + red[2] + red[3]);
    atomicAdd(&stats[2 * m + 1], red2[0] + red2[1] + red2[2] + red2[3]);
  }
}

// ---- merged prep: rqnorm<3> (blocks 0..4095) + wsign (blocks 4096..8191) --
__launch_bounds__(256)
__global__ void prep_kernel(const float* __restrict__ x,
                            const float* __restrict__ w0, const float* __restrict__ w1,
                            const float* __restrict__ w2,
                            char* a0, char* a1, char* a2,
                            float* r0, float* r1, float* r2,
                            const float* wq, const float* wk, const float* wv,
                            const float* wo,
                            char* sq, char* sk, char* sv, char* so,
                            const float* __restrict__ stats) {
  int t = threadIdx.x;
  if (blockIdx.x >= 4096) {
    // ---- ternary sign quant -> int8 ----
    int bid = blockIdx.x - 4096;
    int m = bid >> 10;
    const float* src; char* dst; int n4; float cinv;
    if (m == 0)      { src = wq; dst = sq; n4 = 1048576; cinv = 1.f / 4194304.f; }
    else if (m == 1) { src = wk; dst = sk; n4 = 524288;  cinv = 1.f / 2097152.f; }
    else if (m == 2) { src = wv; dst = sv; n4 = 524288;  cinv = 1.f / 2097152.f; }
    else             { src = wo; dst = so; n4 = 1048576; cinv = 1.f / 4194304.f; }
    float e = stats[2 * m] * cinv;
    for (int i = (bid & 1023) * 256 + t; i < n4; i += 1024 * 256) {
      float4 v = ((const float4*)src)[i];
      char4 o;
      o.x = v.x > e ? 1 : (v.x < e ? -1 : 0);
      o.y = v.y > e ? 1 : (v.y < e ? -1 : 0);
      o.z = v.z > e ? 1 : (v.z < e ? -1 : 0);
      o.w = v.w > e ? 1 : (v.w < e ? -1 : 0);
      ((char4*)dst)[i] = o;
    }
    return;
  }
  // ---- fused RMSNorm + 3-way activation quant -> int8 ----
  __shared__ float red[4];
  __shared__ float redm[4][3];
  int lane = t & 63, w = t >> 6;
  int row = blockIdx.x;
  const float* xr = x + (size_t)row * 2048;
  float4 u0 = ((const float4*)xr)[t * 2], u1 = ((const float4*)xr)[t * 2 + 1];
  float xs[8] = {u0.x, u0.y, u0.z, u0.w, u1.x, u1.y, u1.z, u1.w};
  float ss = 0.f;
#pragma unroll
  for (int e = 0; e < 8; ++e) { xs[e] = clampf(xs[e], -100.f, 100.f); ss += xs[e] * xs[e]; }
  float tot = block_sum(ss, red, lane, w);
  float var = fmaxf(tot * (1.f / 2048.f), 1e-5f);
  float inv = 1.f / sqrtf(var + 1e-5f);
#pragma unroll
  for (int e = 0; e < 8; ++e) xs[e] = clampf(xs[e] * inv, -10.f, 10.f);

  float y[3][8], am[3];
#pragma unroll
  for (int m = 0; m < 3; ++m) {
    const float* wt = (m == 0) ? w0 : (m == 1) ? w1 : w2;
    float4 b0 = ((const float4*)wt)[t * 2], b1 = ((const float4*)wt)[t * 2 + 1];
    float wv8[8] = {b0.x, b0.y, b0.z, b0.w, b1.x, b1.y, b1.z, b1.w};
    am[m] = 0.f;
#pragma unroll
    for (int e = 0; e < 8; ++e) {
      y[m][e] = clampf(wv8[e] * xs[e], -50.f, 50.f);
      am[m] = fmaxf(am[m], fabsf(y[m][e]));
    }
  }
#pragma unroll
  for (int o = 32; o > 0; o >>= 1)
#pragma unroll
    for (int m = 0; m < 3; ++m) am[m] = fmaxf(am[m], __shfl_xor(am[m], o, 64));
  if (lane == 0)
#pragma unroll
    for (int m = 0; m < 3; ++m) redm[w][m] = am[m];
  __syncthreads();
#pragma unroll
  for (int m = 0; m < 3; ++m) {
    char* a = (m == 0) ? a0 : (m == 1) ? a1 : a2;
    float* r = (m == 0) ? r0 : (m == 1) ? r1 : r2;
    float mx = fmaxf(fmaxf(redm[0][m], redm[1][m]), fmaxf(redm[2][m], redm[3][m]));
    float maxval = fmaxf(mx, 1e-4f);
    float sc = 127.f / maxval;
    union { char c[8]; int2 v; } pk;
#pragma unroll
    for (int e = 0; e < 8; ++e)
      pk.c[e] = (char)clampf(rintf(y[m][e] * sc), -128.f, 127.f);
    *(int2*)(a + (size_t)row * 2048 + t * 8) = pk.v;
    if (t == 0) r[row] = maxval * (1.f / 127.f);
  }
}

// ---------------- fused RMSNorm + activation quant -> int8 (1-way) ---------
template <int NW>
__launch_bounds__(256)
__global__ void rqnorm_kernel(const float* __restrict__ x,
                              const float* __restrict__ w0, const float* __restrict__ w1,
                              const float* __restrict__ w2,
                              char* a0, char* a1, char* a2,
                              float* r0, float* r1, float* r2) {
  __shared__ float red[4];
  __shared__ float redm[4][NW];
  int t = threadIdx.x, lane = t & 63, w = t >> 6;
  int row = blockIdx.x;
  const float* xr = x + (size_t)row * 2048;
  float4 u0 = ((const float4*)xr)[t * 2], u1 = ((const float4*)xr)[t * 2 + 1];
  float xs[8] = {u0.x, u0.y, u0.z, u0.w, u1.x, u1.y, u1.z, u1.w};
  float ss = 0.f;
#pragma unroll
  for (int e = 0; e < 8; ++e) { xs[e] = clampf(xs[e], -100.f, 100.f); ss += xs[e] * xs[e]; }
  float tot = block_sum(ss, red, lane, w);
  float var = fmaxf(tot * (1.f / 2048.f), 1e-5f);
  float inv = 1.f / sqrtf(var + 1e-5f);
#pragma unroll
  for (int e = 0; e < 8; ++e) xs[e] = clampf(xs[e] * inv, -10.f, 10.f);

  float y[NW][8], am[NW];
#pragma unroll
  for (int m = 0; m < NW; ++m) {
    const float* wt = (m == 0) ? w0 : (m == 1) ? w1 : w2;
    float4 b0 = ((const float4*)wt)[t * 2], b1 = ((const float4*)wt)[t * 2 + 1];
    float wv8[8] = {b0.x, b0.y, b0.z, b0.w, b1.x, b1.y, b1.z, b1.w};
    am[m] = 0.f;
#pragma unroll
    for (int e = 0; e < 8; ++e) {
      y[m][e] = clampf(wv8[e] * xs[e], -50.f, 50.f);
      am[m] = fmaxf(am[m], fabsf(y[m][e]));
    }
  }
#pragma unroll
  for (int o = 32; o > 0; o >>= 1)
#pragma unroll
    for (int m = 0; m < NW; ++m) am[m] = fmaxf(am[m], __shfl_xor(am[m], o, 64));
  if (lane == 0)
#pragma unroll
    for (int m = 0; m < NW; ++m) redm[w][m] = am[m];
  __syncthreads();
#pragma unroll
  for (int m = 0; m < NW; ++m) {
    char* a = (m == 0) ? a0 : (m == 1) ? a1 : a2;
    float* r = (m == 0) ? r0 : (m == 1) ? r1 : r2;
    float mx = fmaxf(fmaxf(redm[0][m], redm[1][m]), fmaxf(redm[2][m], redm[3][m]));
    float maxval = fmaxf(mx, 1e-4f);
    float sc = 127.f / maxval;
    union { char c[8]; int2 v; } pk;
#pragma unroll
    for (int e = 0; e < 8; ++e)
      pk.c[e] = (char)clampf(rintf(y[m][e] * sc), -128.f, 127.f);
    *(int2*)(a + (size_t)row * 2048 + t * 8) = pk.v;
    if (t == 0) r[row] = maxval * (1.f / 127.f);
  }
}

// ---------------- INT8 GEMM pipeline core, BK=128 (frozen) -----------------
template <int BM, int BN>
DI void mm_pipe(const char* __restrict__ Ag0, const char* __restrict__ Bg0,
                char* As, char* Bs, int t, i32x4 (&acc)[BM / 64][BN / 32]) {
  constexpr int MR = BM / 64, NR = BN / 32;
  constexpr int AL = BM / 64, BL = BN / 64;    // 16B chunks/thread/tile
  constexpr int NT = 16;                       // K = 2048 / 128
  int lane = t & 63, l15 = lane & 15, quad = lane >> 4;
  int wv = t >> 6, wm = wv >> 1, wn = wv & 1;
  const char* agp[AL]; const char* bgp[BL];
#pragma unroll
  for (int i = 0; i < AL; ++i) {
    int c = t + i * 512, row = c >> 3, cr = c & 7;
    agp[i] = Ag0 + (size_t)row * 2048 + (cr ^ (row & 7)) * 16;
  }
#pragma unroll
  for (int i = 0; i < BL; ++i) {
    int c = t + i * 512, row = c >> 3, cr = c & 7;
    bgp[i] = Bg0 + (size_t)row * 2048 + (cr ^ (row & 7)) * 16;
  }
  auto stage = [&](int buf, int kt) {
    int kb = kt * 128;
#pragma unroll
    for (int i = 0; i < AL; ++i)
      gl_lds16(As + buf * (BM * 128) + (t + i * 512) * 16, agp[i] + kb);
#pragma unroll
    for (int i = 0; i < BL; ++i)
      gl_lds16(Bs + buf * (BN * 128) + (t + i * 512) * 16, bgp[i] + kb);
  };
  stage(0, 0);
  stage(1, 1);
  int arow = wm * (BM / 4) + l15;
  int brow = wn * (BN / 2) + l15;
  int sa = arow & 7, sb = brow & 7;
  for (int kt = 0; kt < NT; ++kt) {
    int cur = kt & 1;
    if (kt == NT - 1) wait_vm<0>(); else wait_vm<AL + BL>();
    __builtin_amdgcn_sched_barrier(0);
    __builtin_amdgcn_s_barrier();
    __builtin_amdgcn_sched_barrier(0);
    const char* Ac = As + cur * (BM * 128);
    const char* Bc = Bs + cur * (BN * 128);
    __builtin_amdgcn_s_setprio(1);
#pragma unroll
    for (int ks = 0; ks < 2; ++ks) {
      int aco = ((ks * 4 + quad) ^ sa) * 16;
      int bco = ((ks * 4 + quad) ^ sb) * 16;
      i32x4 af[MR], bfr[NR];
#pragma unroll
      for (int m = 0; m < MR; ++m)
        af[m] = *(const i32x4*)(Ac + (arow + m * 16) * 128 + aco);
#pragma unroll
      for (int n = 0; n < NR; ++n)
        bfr[n] = *(const i32x4*)(Bc + (brow + n * 16) * 128 + bco);
#pragma unroll
      for (int m = 0; m < MR; ++m)
#pragma unroll
        for (int n = 0; n < NR; ++n)
          acc[m][n] = __builtin_amdgcn_mfma_i32_16x16x64_i8(af[m], bfr[n], acc[m][n], 0, 0, 0);
    }
    __builtin_amdgcn_s_setprio(0);
    __builtin_amdgcn_sched_barrier(0);
    __builtin_amdgcn_s_barrier();
    __builtin_amdgcn_sched_barrier(0);
    if (kt + 2 < NT) stage(cur, kt + 2);
  }
}

// ---------------- fused QKV projection GEMM (256x256 tiles, i8, BK=128) ----
__launch_bounds__(512, 2)
__global__ void qkv_gemm(const char* __restrict__ Aq, const char* __restrict__ Ak,
                         const char* __restrict__ Av, const char* __restrict__ Ball,
                         const float* __restrict__ rq, const float* __restrict__ rk,
                         const float* __restrict__ rv, const float* __restrict__ stats,
                         bf16* __restrict__ qr, bf16* __restrict__ kr,
                         bf16* __restrict__ vt,
                         const float* __restrict__ ct, const float* __restrict__ st) {
  __shared__ char As[2 * 256 * 128];  // 64 KB
  __shared__ char Bs[2 * 256 * 128];  // 64 KB  (128 KB total, 1 block/CU)
  int t = threadIdx.x;
  int bid = blockIdx.x;               // 256 blocks
  int swz = (bid & 7) * 32 + (bid >> 3);   // XCD-contiguous chunks (256%8==0)
  int x = swz >> 4, mt = swz & 15;
  int m0 = mt * 256;
  const char* A; const float* rs; float sw;
  if (x < 8)       { A = Aq; rs = rq; sw = stats[1] * (1.f / 4194304.f); }
  else if (x < 12) { A = Ak; rs = rk; sw = stats[3] * (1.f / 2097152.f); }
  else             { A = Av; rs = rv; sw = stats[5] * (1.f / 2097152.f); }
  sw = fmaxf(sw, 1e-8f);
  i32x4 acc[4][8] = {};
  mm_pipe<256, 256>(A + (size_t)m0 * 2048, Ball + (size_t)(x * 256) * 2048, As, Bs, t, acc);

  int lane = t & 63, l15 = lane & 15, quad = lane >> 4;
  int wv = t >> 6, wm = wv >> 1, wn = wv & 1;   // wave cols = wn*128 (one head)
  if (x < 12) {
    // Q pre-scaled by (1/sqrt(128))*log2(e): attn softmax runs in exp2 domain.
    constexpr float QROPE = 0.08838834764831845f * 1.4426950408889634f;
    float qmul = (x < 8) ? QROPE : 1.f;
    bf16* outb = (x < 8) ? qr : kr;
    int h = (x < 8) ? (x * 2 + wn) : ((x - 8) * 2 + wn);
    int nh = (x < 8) ? 16 : 8;
#pragma unroll
    for (int m = 0; m < 4; ++m)
#pragma unroll
      for (int r = 0; r < 4; ++r) {
        int row = m0 + wm * 64 + m * 16 + quad * 4 + r;
        float rsc = rs[row] * sw * qmul;
        int s = row & 2047, b = row >> 11;
        size_t base = ((size_t)(b * nh + h) * 2048 + s) * 128;
#pragma unroll
        for (int n = 0; n < 4; ++n) {
          int d = n * 16 + l15;
          float x1 = (float)acc[m][n][r] * rsc;
          float x2 = (float)acc[m][n + 4][r] * rsc;
          float c = ct[s * 64 + d], sn = st[s * 64 + d];
          outb[base + d]      = (bf16)(x1 * c - x2 * sn);
          outb[base + d + 64] = (bf16)(x2 * c + x1 * sn);
        }
      }
  } else {
    // V^T epilogue: wave's 128 cols = one kv-head; 4 consecutive tokens per
    // lane (r) -> bf16x4 store at V^T[(b*8+kvh)*128 + d][s0..s0+3].
    int n0g = (x - 12) * 256 + wn * 128;
    int kvh = n0g >> 7;
    int btok = m0 >> 11;
    int s0 = (m0 & 2047) + wm * 64 + quad * 4;
#pragma unroll
    for (int m = 0; m < 4; ++m)
#pragma unroll
      for (int n = 0; n < 8; ++n) {
        int d = n * 16 + l15;
        bf16x4 pk;
#pragma unroll
        for (int r = 0; r < 4; ++r) {
          int row = m0 + wm * 64 + m * 16 + quad * 4 + r;
          pk[r] = (bf16)((float)acc[m][n][r] * (rs[row] * sw));
        }
        *(bf16x4*)(vt + ((size_t)(btok * 8 + kvh) * 128 + d) * 2048 + s0 + m * 16) = pk;
      }
  }
}

// ---------------- O projection GEMM (128x256 tiles, i8, BK=128) ------------
__launch_bounds__(512, 2)
__global__ void gemm_o(const char* __restrict__ A, const char* __restrict__ Bw,
                       const float* __restrict__ rs, const float* __restrict__ stats,
                       float* __restrict__ out) {
  __shared__ char As[2 * 128 * 128];  // 32 KB
  __shared__ char Bs[2 * 256 * 128];  // 64 KB  (96 KB total)
  int t = threadIdx.x;
  int bid = blockIdx.x;               // 256 blocks
  int swz = (bid & 7) * 32 + (bid >> 3);
  int x = swz & 7, mt = swz >> 3;     // n-tile 0..7, m-tile 0..31
  int m0 = mt * 128, n0 = x * 256;
  i32x4 acc[2][8] = {};
  mm_pipe<128, 256>(A + (size_t)m0 * 2048, Bw + (size_t)n0 * 2048, As, Bs, t, acc);
  float sw = fmaxf(stats[7] * (1.f / 4194304.f), 1e-8f);
  int lane = t & 63, l15 = lane & 15, quad = lane >> 4;
  int wv = t >> 6, wm = wv >> 1, wn = wv & 1;
#pragma unroll
  for (int m = 0; m < 2; ++m)
#pragma unroll
    for (int r = 0; r < 4; ++r) {
      int row = m0 + wm * 32 + m * 16 + quad * 4 + r;
      float rsc = rs[row] * sw;
#pragma unroll
      for (int n = 0; n < 8; ++n)
        out[(size_t)row * 2048 + n0 + wn * 128 + n * 16 + l15] = (float)acc[m][n][r] * rsc;
    }
}

// ---------------- flash attention, S^T formulation, 8 waves ----------------
// (R13-proven version: 125us, VGPR=64, LDS-Ps PV with b128 reads)
__launch_bounds__(512, 4)
__global__ void attn_kernel(const bf16* __restrict__ Q, const bf16* __restrict__ Kc,
                            const bf16* __restrict__ Vt, const float* __restrict__ mask,
                            float* __restrict__ Oout) {
  constexpr float L2E  = 1.4426950408889634f;
  constexpr float DTHR = 8.f * L2E;
  __shared__ bf16 Ks[2][64 * 128];
  __shared__ bf16 Vs[2][128 * 64];
  __shared__ bf16 Ps[128 * 64];
  int t = threadIdx.x, w = t >> 6, lane = t & 63;
  int l15 = lane & 15, quad = lane >> 4;
  int bh = blockIdx.y, b = bh >> 4, h = bh & 15, kvh = h >> 1;
  int q0 = blockIdx.x * 128;
  const bf16* Qb = Q + (size_t)(b * 16 + h) * 2048 * 128;
  const bf16* Kb = Kc + (size_t)(b * 8 + kvh) * 2048 * 128;
  const bf16* Vb = Vt + (size_t)(b * 8 + kvh) * 128 * 2048;

  int qloc = w * 16 + l15;
  int qg = q0 + qloc;

  bf16x8 qf[4];
#pragma unroll
  for (int kc = 0; kc < 4; ++kc)
    qf[kc] = *(const bf16x8*)(Qb + (size_t)qg * 128 + kc * 32 + quad * 8);

  f32x4 Oa[8] = {};
  float mrow = -1e30f, lrow = 0.f;

  auto stage = [&](int buf, int kt) {
    int kk0 = kt * 64;
#pragma unroll
    for (int i = 0; i < 2; ++i) {
      int c = t + i * 512;
      int kr = c >> 4, c16 = c & 15;
      gl_lds16(&Ks[buf][c * 8],
               Kb + (size_t)(kk0 + kr) * 128 + ((c16 ^ (kr & 15)) * 8));
    }
#pragma unroll
    for (int i = 0; i < 2; ++i) {
      int c = t + i * 512;
      int vr = c >> 3, c8 = c & 7;
      gl_lds16(&Vs[buf][c * 8],
               Vb + (size_t)vr * 2048 + kk0 + ((c8 ^ (vr & 7)) * 8));
    }
  };

  stage(0, 0);

  f32x4 mv[4];
#pragma unroll
  for (int k2 = 0; k2 < 4; ++k2)
    mv[k2] = *(const f32x4*)(mask + (size_t)qg * 2048 + k2 * 16 + quad * 4);

  for (int kt = 0; kt < 32; ++kt) {
    int cur = kt & 1;
    __syncthreads();
    if (kt < 31) stage(cur ^ 1, kt + 1);

    f32x4 Sacc[4] = {};
    __builtin_amdgcn_s_setprio(1);
#pragma unroll
    for (int kc = 0; kc < 4; ++kc) {
      bf16x8 kf[4];
#pragma unroll
      for (int k2 = 0; k2 < 4; ++k2)
        kf[k2] = *(const bf16x8*)(&Ks[cur][(k2 * 16 + l15) * 128 + (((kc * 4 + quad) ^ l15) * 8)]);
#pragma unroll
      for (int k2 = 0; k2 < 4; ++k2)
        Sacc[k2] = __builtin_amdgcn_mfma_f32_16x16x32_bf16(kf[k2], qf[kc], Sacc[k2], 0, 0, 0);
    }
    __builtin_amdgcn_s_setprio(0);

#pragma unroll
    for (int k2 = 0; k2 < 4; ++k2)
#pragma unroll
      for (int r = 0; r < 4; ++r)
        Sacc[k2][r] = fmaf(mv[k2][r], L2E, Sacc[k2][r]);
    f32x4 vm;
#pragma unroll
    for (int r = 0; r < 4; ++r)
      vm[r] = fmaxf(fmaxf(Sacc[0][r], Sacc[1][r]), fmaxf(Sacc[2][r], Sacc[3][r]));
    float mx = fmaxf(fmaxf(vm[0], vm[1]), fmaxf(vm[2], vm[3]));
    mx = fmaxf(mx, __shfl_xor(mx, 16, 64));
    mx = fmaxf(mx, __shfl_xor(mx, 32, 64));
    if (!__all(mx <= mrow + DTHR)) {
      float mnew = fmaxf(mrow, mx);
      float alpha = exp2f(mrow - mnew);
      mrow = mnew;
      lrow *= alpha;
#pragma unroll
      for (int dt = 0; dt < 8; ++dt) Oa[dt] *= alpha;
    }
    f32x4 vs = {0.f, 0.f, 0.f, 0.f};
#pragma unroll
    for (int k2 = 0; k2 < 4; ++k2) {
      bf16x4 pk;
#pragma unroll
      for (int r = 0; r < 4; ++r) {
        float p = exp2f(Sacc[k2][r] - mrow);
        vs[r] += p;
        pk[r] = (bf16)p;
      }
      int c = k2 * 2 + (quad >> 1);
      *(bf16x4*)(&Ps[qloc * 64 + ((c ^ (qloc & 7)) * 8) + (quad & 1) * 4]) = pk;
    }
    float rsum = (vs[0] + vs[1]) + (vs[2] + vs[3]);
    rsum += __shfl_xor(rsum, 16, 64);
    rsum += __shfl_xor(rsum, 32, 64);
    lrow += rsum;

    if (kt < 31) {
      int kk1 = (kt + 1) * 64;
#pragma unroll
      for (int k2 = 0; k2 < 4; ++k2)
        mv[k2] = *(const f32x4*)(mask + (size_t)qg * 2048 + kk1 + k2 * 16 + quad * 4);
    }

    __builtin_amdgcn_s_setprio(1);
#pragma unroll
    for (int kc = 0; kc < 2; ++kc) {
      bf16x8 pf = *(const bf16x8*)(&Ps[qloc * 64 + (((kc * 4 + quad) ^ (l15 & 7)) * 8)]);
#pragma unroll
      for (int dt = 0; dt < 8; ++dt) {
        bf16x8 vf = *(const bf16x8*)(&Vs[cur][(dt * 16 + l15) * 64 +
                                              (((kc * 4 + quad) ^ (l15 & 7)) * 8)]);
        Oa[dt] = __builtin_amdgcn_mfma_f32_16x16x32_bf16(vf, pf, Oa[dt], 0, 0, 0);
      }
    }
    __builtin_amdgcn_s_setprio(0);
  }

  float inv = 1.f / lrow;
  int token = b * 2048 + qg;
#pragma unroll
  for (int dt = 0; dt < 8; ++dt) {
    f32x4 o = Oa[dt] * inv;
    *(f32x4*)(Oout + (size_t)token * 2048 + h * 128 + dt * 16 + quad * 4) = o;
  }
}

// ---------------- launch ----------------
extern "C" void kernel_launch(void* const* d_in, const int* in_sizes, int n_in,
                              void* d_out, int out_size, void* d_ws, size_t ws_size,
                              hipStream_t stream) {
  const float* hidden = (const float*)d_in[0];
  const float* mask   = (const float*)d_in[1];
  const float* wq = (const float*)d_in[2];
  const float* wk = (const float*)d_in[3];
  const float* wv = (const float*)d_in[4];
  const float* wo = (const float*)d_in[5];
  const float* nq = (const float*)d_in[6];
  const float* nk = (const float*)d_in[7];
  const float* nv = (const float*)d_in[8];
  const float* no = (const float*)d_in[9];
  float* out = (float*)d_out;
  char* ws = (char*)d_ws;

  // i8 weights: SQ|SK|SV|SO contiguous (Ball = SQ base).
  constexpr size_t O_STATS = 0;
  constexpr size_t O_CT    = 256;
  constexpr size_t O_ST    = O_CT  + 524288;
  constexpr size_t O_SQ    = O_ST  + 524288;
  constexpr size_t O_SK    = O_SQ  + 4194304;
  constexpr size_t O_SV    = O_SK  + 2097152;
  constexpr size_t O_SO    = O_SV  + 2097152;
  constexpr size_t O_RSQ   = O_SO  + 4194304;
  constexpr size_t O_RSK   = O_RSQ + 16384;
  constexpr size_t O_RSV   = O_RSK + 16384;
  constexpr size_t O_RSO   = O_RSV + 16384;
  constexpr size_t O_AQQ   = O_RSO + 16384;     // i8 [4096][2048]
  constexpr size_t O_AQK   = O_AQQ + 8388608;
  constexpr size_t O_AQV   = O_AQK + 8388608;
  constexpr size_t O_QR    = O_AQV + 8388608;   // bf16 [2,16,2048,128]
  constexpr size_t O_KR    = O_QR  + 16777216;  // bf16 [2,8,2048,128]
  constexpr size_t O_VT    = O_KR  + 8388608;   // bf16 [2,8,128,2048]
  constexpr size_t O_ATTN  = O_VT  + 8388608;   // fp32 [4096,2048]
  constexpr size_t O_AQO   = O_AQQ;             // alias: i8, AQQ dead post-qkv

  float* stats = (float*)(ws + O_STATS);
  float* ct = (float*)(ws + O_CT);
  float* st = (float*)(ws + O_ST);

  (void)hipMemsetAsync(ws + O_STATS, 0, 256, stream);

  wstats_kernel<<<dim3(256, 5), 256, 0, stream>>>(wq, wk, wv, wo, stats, ct, st);

  prep_kernel<<<dim3(8192), 256, 0, stream>>>(hidden, nq, nk, nv,
      ws + O_AQQ, ws + O_AQK, ws + O_AQV,
      (float*)(ws + O_RSQ), (float*)(ws + O_RSK), (float*)(ws + O_RSV),
      wq, wk, wv, wo,
      ws + O_SQ, ws + O_SK, ws + O_SV, ws + O_SO, stats);

  qkv_gemm<<<dim3(256), 512, 0, stream>>>(
      ws + O_AQQ, ws + O_AQK, ws + O_AQV, ws + O_SQ,
      (const float*)(ws + O_RSQ), (const float*)(ws + O_RSK), (const float*)(ws + O_RSV),
      stats, (bf16*)(ws + O_QR), (bf16*)(ws + O_KR), (bf16*)(ws + O_VT), ct, st);

  attn_kernel<<<dim3(16, 32), 512, 0, stream>>>(
      (const bf16*)(ws + O_QR), (const bf16*)(ws + O_KR), (const bf16*)(ws + O_VT),
      mask, (float*)(ws + O_ATTN));

  rqnorm_kernel<1><<<dim3(4096), 256, 0, stream>>>((const float*)(ws + O_ATTN), no, no, no,
      ws + O_AQO, ws + O_AQO, ws + O_AQO,
      (float*)(ws + O_RSO), (float*)(ws + O_RSO), (float*)(ws + O_RSO));

  gemm_o<<<dim3(256), 512, 0, stream>>>(
      ws + O_AQO, ws + O_SO, (float*)(ws + O_RSO), stats, out);

  (void)in_sizes; (void)n_in; (void)out_size; (void)ws_size;
}